// Round 1
// baseline (926.615 us; speedup 1.0000x reference)
//
#include <hip/hip_runtime.h>
#include <hip/hip_bf16.h>

// ---------------------------------------------------------------------------
// IterativeVoxelModel: 3-layer windowed attention over B=256 patches of 3^3
// voxels. N = B*27 = 6912 tokens, d=256, heads=8 (hd=32), ffn=1024.
// Key trick: K/V projections are computed once per token (not per gathered
// neighbor); attention gathers K/V *rows* via index math. Zero-padded
// neighbors are always masked, so their K/V values are irrelevant.
// ---------------------------------------------------------------------------

#define NTOK 6912      // 256 * 27
#define DM   256
#define FF   1024
#define NHEAD 8
#define HD   32

// ---------------- embed: t = np * w_in + b_in + pos_embed ------------------
__global__ __launch_bounds__(256) void embed_kernel(
    const float* __restrict__ npat, const float* __restrict__ w_in,
    const float* __restrict__ b_in, const float* __restrict__ pos,
    float* __restrict__ t)
{
    int n = blockIdx.x;            // token
    int c = threadIdx.x;           // channel
    int p = n % 27;                // voxel position within patch
    float xv = npat[n];            // (B,1,3,3,3) flat == n
    t[(size_t)n * DM + c] = xv * w_in[c] + b_in[c] + pos[p * DM + c];
}

// ---------------- mask: 27-bit neighborhood mask per token -----------------
__global__ void make_mask_kernel(const int* __restrict__ km,
                                 unsigned int* __restrict__ maskbits)
{
    int n = blockIdx.x * blockDim.x + threadIdx.x;
    if (n >= NTOK) return;
    int b = n / 27, p = n % 27;
    int zc = p / 9, yc = (p / 3) % 3, xc = p % 3;
    unsigned int mb = 0u;
    for (int j = 0; j < 27; ++j) {
        int z = zc + j / 9 - 1;
        int y = yc + (j / 3) % 3 - 1;
        int x = xc + j % 3 - 1;
        if (z >= 0 && z < 3 && y >= 0 && y < 3 && x >= 0 && x < 3 &&
            km[b * 27 + z * 9 + y * 3 + x] != 0)
            mb |= (1u << j);
    }
    maskbits[n] = mb;
}

// ---------------- layernorm over d=256, one block per token ----------------
__global__ __launch_bounds__(256) void layernorm_kernel(
    const float* __restrict__ X, const float* __restrict__ g,
    const float* __restrict__ bta, float* __restrict__ Y)
{
    int n = blockIdx.x;
    int c = threadIdx.x;
    float x = X[(size_t)n * DM + c];
    float s = x, s2 = x * x;
    for (int off = 32; off; off >>= 1) {
        s  += __shfl_xor(s, off);
        s2 += __shfl_xor(s2, off);
    }
    __shared__ float ps[4], ps2[4];
    int w = c >> 6;
    if ((c & 63) == 0) { ps[w] = s; ps2[w] = s2; }
    __syncthreads();
    s  = ps[0] + ps[1] + ps[2] + ps[3];
    s2 = ps2[0] + ps2[1] + ps2[2] + ps2[3];
    float mu  = s * (1.0f / DM);
    float var = s2 * (1.0f / DM) - mu * mu;
    float r = rsqrtf(var + 1e-5f);
    Y[(size_t)n * DM + c] = (x - mu) * r * g[c] + bta[c];
}

// ---------------- fp32 tiled GEMM: C = A[M,K] @ W[K,Nc] + bias -------------
// optional residual add and exact-GELU activation in epilogue.
#define BM 64
#define BN 64
#define BKT 64
#define LPAD 68   // padded LDS stride (floats); 68*4=272B, 16B aligned rows

__global__ __launch_bounds__(256) void gemm_f32(
    const float* __restrict__ A, const float* __restrict__ W,
    const float* __restrict__ bias, const float* __restrict__ residual,
    float* __restrict__ C, int M, int K, int Nc, int act)
{
    __shared__ float As[BKT][LPAD];   // transposed: As[k][m]
    __shared__ float Ws[BKT][LPAD];   // Ws[k][n]
    int tid = threadIdx.x;
    int row0 = blockIdx.x * BM;
    int col0 = blockIdx.y * BN;
    int tn = tid & 15, tm = tid >> 4;
    float acc[4][4] = {};

    for (int k0 = 0; k0 < K; k0 += BKT) {
        __syncthreads();
#pragma unroll
        for (int i = 0; i < 4; ++i) {
            int idx = tid + i * 256;        // 0..1023 float4 slots
            int r   = idx >> 4;             // 0..63
            int c4  = (idx & 15) << 2;      // 0,4,...,60
            float4 a = *(const float4*)&A[(size_t)(row0 + r) * K + k0 + c4];
            As[c4 + 0][r] = a.x; As[c4 + 1][r] = a.y;
            As[c4 + 2][r] = a.z; As[c4 + 3][r] = a.w;
            float4 w = *(const float4*)&W[(size_t)(k0 + r) * Nc + col0 + c4];
            *(float4*)&Ws[r][c4] = w;
        }
        __syncthreads();
#pragma unroll
        for (int kk = 0; kk < BKT; ++kk) {
            float4 a4 = *(const float4*)&As[kk][tm * 4];
            float4 b4 = *(const float4*)&Ws[kk][tn * 4];
            float av[4] = {a4.x, a4.y, a4.z, a4.w};
            float bv[4] = {b4.x, b4.y, b4.z, b4.w};
#pragma unroll
            for (int i = 0; i < 4; ++i)
#pragma unroll
                for (int j = 0; j < 4; ++j)
                    acc[i][j] = fmaf(av[i], bv[j], acc[i][j]);
        }
    }

#pragma unroll
    for (int i = 0; i < 4; ++i) {
        int row = row0 + tm * 4 + i;
#pragma unroll
        for (int j = 0; j < 4; ++j) {
            int col = col0 + tn * 4 + j;
            float v = acc[i][j] + bias[col];
            if (residual) v += residual[(size_t)row * Nc + col];
            if (act == 1) v = 0.5f * v * (1.0f + erff(v * 0.70710678118654752f));
            C[(size_t)row * Nc + col] = v;
        }
    }
}

// ---------------- windowed attention, one block per token ------------------
__global__ __launch_bounds__(256) void attention_kernel(
    const float* __restrict__ Q, const float* __restrict__ K,
    const float* __restrict__ V, const unsigned int* __restrict__ maskbits,
    float* __restrict__ out)
{
    int n = blockIdx.x;
    int tid = threadIdx.x;              // tid = h*32 + d
    int b = n / 27, p = n % 27;
    int zc = p / 9, yc = (p / 3) % 3, xc = p % 3;
    unsigned int mb = maskbits[n];
    float qv = Q[(size_t)n * DM + tid];

    float s[27];
    float mx = -1e30f;
#pragma unroll
    for (int j = 0; j < 27; ++j) {
        if (mb & (1u << j)) {
            int z = zc + j / 9 - 1;
            int y = yc + (j / 3) % 3 - 1;
            int x = xc + j % 3 - 1;
            int m = b * 27 + z * 9 + y * 3 + x;
            float partial = qv * K[(size_t)m * DM + tid];
            for (int off = 16; off; off >>= 1)
                partial += __shfl_xor(partial, off, 32);
            s[j] = partial * 0.17677669529663687f;   // 1/sqrt(32)
            mx = fmaxf(mx, s[j]);
        } else {
            s[j] = -1e30f;
        }
    }
    float sum = 0.f;
#pragma unroll
    for (int j = 0; j < 27; ++j) {
        if (mb & (1u << j)) { s[j] = expf(s[j] - mx); sum += s[j]; }
        else s[j] = 0.f;
    }
    float inv = (sum > 0.f) ? 1.f / sum : 0.f;   // fully-masked row -> 0
    float o = 0.f;
#pragma unroll
    for (int j = 0; j < 27; ++j) {
        if (mb & (1u << j)) {
            int z = zc + j / 9 - 1;
            int y = yc + (j / 3) % 3 - 1;
            int x = xc + j % 3 - 1;
            int m = b * 27 + z * 9 + y * 3 + x;
            o = fmaf(s[j] * inv, V[(size_t)m * DM + tid], o);
        }
    }
    out[(size_t)n * DM + tid] = o;
}

// ---------------- output: out[b] = t[center(b)] . w_out + b_out ------------
__global__ __launch_bounds__(256) void out_proj_kernel(
    const float* __restrict__ t, const float* __restrict__ w_out,
    const float* __restrict__ b_out, float* __restrict__ out)
{
    int bb = blockIdx.x;
    int c = threadIdx.x;
    float v = t[(size_t)(bb * 27 + 13) * DM + c] * w_out[c];
    for (int off = 32; off; off >>= 1) v += __shfl_xor(v, off);
    __shared__ float ps[4];
    if ((c & 63) == 0) ps[c >> 6] = v;
    __syncthreads();
    if (c == 0) out[bb] = ps[0] + ps[1] + ps[2] + ps[3] + b_out[0];
}

// ---------------------------------------------------------------------------
extern "C" void kernel_launch(void* const* d_in, const int* in_sizes, int n_in,
                              void* d_out, int out_size, void* d_ws, size_t ws_size,
                              hipStream_t stream)
{
    const float* npat  = (const float*)d_in[0];
    const int*   kmask = (const int*)  d_in[1];
    const float* w_in  = (const float*)d_in[2];
    const float* b_in  = (const float*)d_in[3];
    const float* pos   = (const float*)d_in[4];
    const float* ln1_g = (const float*)d_in[5];
    const float* ln1_b = (const float*)d_in[6];
    const float* ln2_g = (const float*)d_in[7];
    const float* ln2_b = (const float*)d_in[8];
    const float* Wq    = (const float*)d_in[9];
    const float* bq    = (const float*)d_in[10];
    const float* Wk    = (const float*)d_in[11];
    const float* bk    = (const float*)d_in[12];
    const float* Wv    = (const float*)d_in[13];
    const float* bv    = (const float*)d_in[14];
    const float* Wo    = (const float*)d_in[15];
    const float* bo    = (const float*)d_in[16];
    const float* W1    = (const float*)d_in[17];
    const float* b1    = (const float*)d_in[18];
    const float* W2    = (const float*)d_in[19];
    const float* b2    = (const float*)d_in[20];
    const float* w_out = (const float*)d_in[21];
    const float* b_out = (const float*)d_in[22];
    float* out = (float*)d_out;

    // workspace carve-up (all 256B-aligned)
    char* ws = (char*)d_ws;
    size_t tokmat = (size_t)NTOK * DM * sizeof(float);      // 7,077,888 B
    float* t    = (float*)(ws);
    float* tn   = (float*)(ws + tokmat);
    float* Qb   = (float*)(ws + 2 * tokmat);
    float* Kb   = (float*)(ws + 3 * tokmat);
    float* Vb   = (float*)(ws + 4 * tokmat);
    float* attn = (float*)(ws + 5 * tokmat);
    float* Hb   = (float*)(ws + 6 * tokmat);                 // N x 1024
    unsigned int* maskbits = (unsigned int*)(ws + 6 * tokmat + (size_t)NTOK * FF * sizeof(float));

    embed_kernel<<<NTOK, 256, 0, stream>>>(npat, w_in, b_in, pos, t);
    make_mask_kernel<<<(NTOK + 255) / 256, 256, 0, stream>>>(kmask, maskbits);

    dim3 g256(NTOK / BM, DM / BN);    // (108, 4)
    dim3 gFF1(NTOK / BM, FF / BN);    // (108, 16)

    for (int l = 0; l < 3; ++l) {
        const float* wq = Wq + (size_t)l * DM * DM;
        const float* wk = Wk + (size_t)l * DM * DM;
        const float* wv = Wv + (size_t)l * DM * DM;
        const float* wo = Wo + (size_t)l * DM * DM;
        const float* w1 = W1 + (size_t)l * DM * FF;
        const float* w2 = W2 + (size_t)l * FF * DM;

        layernorm_kernel<<<NTOK, 256, 0, stream>>>(t, ln1_g + l * DM, ln1_b + l * DM, tn);
        gemm_f32<<<g256, 256, 0, stream>>>(tn, wq, bq + l * DM, nullptr, Qb, NTOK, DM, DM, 0);
        gemm_f32<<<g256, 256, 0, stream>>>(t,  wk, bk + l * DM, nullptr, Kb, NTOK, DM, DM, 0);
        gemm_f32<<<g256, 256, 0, stream>>>(t,  wv, bv + l * DM, nullptr, Vb, NTOK, DM, DM, 0);
        attention_kernel<<<NTOK, 256, 0, stream>>>(Qb, Kb, Vb, maskbits, attn);
        gemm_f32<<<g256, 256, 0, stream>>>(attn, wo, bo + l * DM, t, t, NTOK, DM, DM, 0);
        layernorm_kernel<<<NTOK, 256, 0, stream>>>(t, ln2_g + l * DM, ln2_b + l * DM, tn);
        gemm_f32<<<gFF1, 256, 0, stream>>>(tn, w1, b1 + l * FF, nullptr, Hb, NTOK, DM, FF, 1);
        gemm_f32<<<g256, 256, 0, stream>>>(Hb, w2, b2 + l * DM, t, t, NTOK, FF, DM, 0);
    }

    out_proj_kernel<<<256, 256, 0, stream>>>(t, w_out, b_out, out);
}

// Round 2
// 550.081 us; speedup vs baseline: 1.6845x; 1.6845x over previous
//
#include <hip/hip_runtime.h>
#include <hip/hip_bf16.h>

// ---------------------------------------------------------------------------
// IterativeVoxelModel: 3-layer windowed attention. N = 256*27 = 6912 tokens,
// d=256, heads=8 (hd=32), ffn=1024.
// R2: all GEMMs moved to bf16 MFMA (16x16x32), fp32 residual stream.
// K/V projections computed once per token; attention gathers K/V rows.
// ---------------------------------------------------------------------------

#define NTOK 6912
#define DM   256
#define FF   1024

typedef __hip_bfloat16 bf16;
typedef __bf16 bf16x8 __attribute__((ext_vector_type(8)));
typedef float  f32x4  __attribute__((ext_vector_type(4)));

__device__ __forceinline__ void gload_lds16(const void* g, void* l) {
    __builtin_amdgcn_global_load_lds(
        (const __attribute__((address_space(1))) void*)g,
        (__attribute__((address_space(3))) void*)l, 16, 0, 0);
}

// ---------------- embed: t = np * w_in + b_in + pos_embed ------------------
__global__ __launch_bounds__(256) void embed_kernel(
    const float* __restrict__ npat, const float* __restrict__ w_in,
    const float* __restrict__ b_in, const float* __restrict__ pos,
    float* __restrict__ t, bf16* __restrict__ t_bf)
{
    int n = blockIdx.x;
    int c = threadIdx.x;
    int p = n % 27;
    float v = npat[n] * w_in[c] + b_in[c] + pos[p * DM + c];
    t[(size_t)n * DM + c] = v;
    t_bf[(size_t)n * DM + c] = __float2bfloat16(v);
}

// ---------------- mask: 27-bit neighborhood mask per token -----------------
__global__ void make_mask_kernel(const int* __restrict__ km,
                                 unsigned int* __restrict__ maskbits)
{
    int n = blockIdx.x * blockDim.x + threadIdx.x;
    if (n >= NTOK) return;
    int b = n / 27, p = n % 27;
    int zc = p / 9, yc = (p / 3) % 3, xc = p % 3;
    unsigned int mb = 0u;
    for (int j = 0; j < 27; ++j) {
        int z = zc + j / 9 - 1;
        int y = yc + (j / 3) % 3 - 1;
        int x = xc + j % 3 - 1;
        if (z >= 0 && z < 3 && y >= 0 && y < 3 && x >= 0 && x < 3 &&
            km[b * 27 + z * 9 + y * 3 + x] != 0)
            mb |= (1u << j);
    }
    maskbits[n] = mb;
}

// ---------------- weight convert+transpose: W[K][N] f32 -> Wt[N][K] bf16 ---
// z: 18 matrices, layout per layer: Wq,Wk,Wv,Wo (256x256), W1 (256->1024),
// W2 (1024->256). Per-layer stride = 4*65536 + 2*262144 = 786432 elements.
__global__ __launch_bounds__(256) void convert_weights(
    const float* __restrict__ Wq, const float* __restrict__ Wk,
    const float* __restrict__ Wv, const float* __restrict__ Wo,
    const float* __restrict__ W1, const float* __restrict__ W2,
    bf16* __restrict__ Wt)
{
    __shared__ float tile[32][33];
    int id = blockIdx.z;
    int l = id / 6, wsel = id % 6;
    const float* src; bf16* dst; int K, N;
    if (wsel < 4) {
        const float* tbl[4] = {Wq, Wk, Wv, Wo};
        src = tbl[wsel] + (size_t)l * 65536; K = 256; N = 256;
        dst = Wt + (size_t)l * 786432 + wsel * 65536;
    } else if (wsel == 4) {
        src = W1 + (size_t)l * 262144; K = 256; N = 1024;
        dst = Wt + (size_t)l * 786432 + 262144;
    } else {
        src = W2 + (size_t)l * 262144; K = 1024; N = 256;
        dst = Wt + (size_t)l * 786432 + 524288;
    }
    int n0 = blockIdx.x * 32, k0 = blockIdx.y * 32;
    if (n0 >= N || k0 >= K) return;
    int tx = threadIdx.x, ty = threadIdx.y;   // 32 x 8
#pragma unroll
    for (int i = 0; i < 4; ++i)
        tile[ty + i * 8][tx] = src[(size_t)(k0 + ty + i * 8) * N + n0 + tx];
    __syncthreads();
#pragma unroll
    for (int i = 0; i < 4; ++i)
        dst[(size_t)(n0 + ty + i * 8) * K + k0 + tx] =
            __float2bfloat16(tile[tx][ty + i * 8]);
}

// ---------------- layernorm over d=256, one block per token ----------------
__global__ __launch_bounds__(256) void layernorm_kernel(
    const float* __restrict__ X, const float* __restrict__ g,
    const float* __restrict__ bta, bf16* __restrict__ Y)
{
    int n = blockIdx.x;
    int c = threadIdx.x;
    float x = X[(size_t)n * DM + c];
    float s = x, s2 = x * x;
    for (int off = 32; off; off >>= 1) {
        s  += __shfl_xor(s, off);
        s2 += __shfl_xor(s2, off);
    }
    __shared__ float ps[4], ps2[4];
    int w = c >> 6;
    if ((c & 63) == 0) { ps[w] = s; ps2[w] = s2; }
    __syncthreads();
    s  = ps[0] + ps[1] + ps[2] + ps[3];
    s2 = ps2[0] + ps2[1] + ps2[2] + ps2[3];
    float mu  = s * (1.0f / DM);
    float var = s2 * (1.0f / DM) - mu * mu;
    float r = rsqrtf(var + 1e-5f);
    Y[(size_t)n * DM + c] = __float2bfloat16((x - mu) * r * g[c] + bta[c]);
}

// ---------------- bf16 MFMA GEMM: C = A[M,K] @ Bt[N,K]^T + bias ------------
// 128x64 tile, 4 waves (2x2), each wave 64x32 = 4x2 fragments of 16x16.
// BK=64, global_load_lds staging, fp32 accum. Optional residual (f32),
// exact GELU, dual f32/bf16 output.
__global__ __launch_bounds__(256) void gemm_bf16(
    const bf16* __restrict__ A, const bf16* __restrict__ Bt,
    const float* __restrict__ bias, const float* __restrict__ residual,
    float* __restrict__ Cf, bf16* __restrict__ Cb,
    int K, int Nc, int act)
{
    __shared__ __align__(16) bf16 As[128 * 64];
    __shared__ __align__(16) bf16 Bs[64 * 64];
    int tid = threadIdx.x;
    int wv = tid >> 6, ln = tid & 63;
    int wr = wv >> 1, wc = wv & 1;
    int row0 = blockIdx.x * 128;
    int col0 = blockIdx.y * 64;

    f32x4 acc[4][2];
#pragma unroll
    for (int m = 0; m < 4; ++m)
#pragma unroll
        for (int n = 0; n < 2; ++n) acc[m][n] = (f32x4){0.f, 0.f, 0.f, 0.f};

    int lrow = ln >> 3;          // 0..7 row within 1KB chunk
    int kof  = (ln & 7) * 8;     // bf16 offset within 64-elem row

    for (int k0 = 0; k0 < K; k0 += 64) {
        __syncthreads();
#pragma unroll
        for (int i = 0; i < 4; ++i) {
            int slot = i * 4 + wv;                    // 0..15 (8 rows each)
            gload_lds16(A + (size_t)(row0 + slot * 8 + lrow) * K + k0 + kof,
                        As + slot * 512);
        }
#pragma unroll
        for (int i = 0; i < 2; ++i) {
            int slot = i * 4 + wv;                    // 0..7
            gload_lds16(Bt + (size_t)(col0 + slot * 8 + lrow) * K + k0 + kof,
                        Bs + slot * 512);
        }
        __syncthreads();
        int lr = ln & 15, kg = ln >> 4;
#pragma unroll
        for (int kk = 0; kk < 2; ++kk) {
            int koff = kk * 32 + kg * 8;
            bf16x8 a[4], b[2];
#pragma unroll
            for (int m = 0; m < 4; ++m)
                a[m] = *(const bf16x8*)&As[(wr * 64 + m * 16 + lr) * 64 + koff];
#pragma unroll
            for (int n = 0; n < 2; ++n)
                b[n] = *(const bf16x8*)&Bs[(wc * 32 + n * 16 + lr) * 64 + koff];
#pragma unroll
            for (int m = 0; m < 4; ++m)
#pragma unroll
                for (int n = 0; n < 2; ++n)
                    acc[m][n] = __builtin_amdgcn_mfma_f32_16x16x32_bf16(
                        a[m], b[n], acc[m][n], 0, 0, 0);
        }
    }

    int lr = ln & 15, rg = ln >> 4;
#pragma unroll
    for (int m = 0; m < 4; ++m) {
#pragma unroll
        for (int n = 0; n < 2; ++n) {
            int col = col0 + wc * 32 + n * 16 + lr;
            float bcol = bias[col];
#pragma unroll
            for (int r = 0; r < 4; ++r) {
                int row = row0 + wr * 64 + m * 16 + rg * 4 + r;
                size_t idx = (size_t)row * Nc + col;
                float v = acc[m][n][r] + bcol;
                if (residual) v += residual[idx];
                if (act) v = 0.5f * v * (1.0f + erff(v * 0.70710678118654752f));
                if (Cf) Cf[idx] = v;
                if (Cb) Cb[idx] = __float2bfloat16(v);
            }
        }
    }
}

// ---------------- windowed attention, one block per token ------------------
__global__ __launch_bounds__(256) void attention_kernel(
    const float* __restrict__ Q, const float* __restrict__ K,
    const float* __restrict__ V, const unsigned int* __restrict__ maskbits,
    bf16* __restrict__ out)
{
    int n = blockIdx.x;
    int tid = threadIdx.x;              // tid = h*32 + d
    int b = n / 27, p = n % 27;
    int zc = p / 9, yc = (p / 3) % 3, xc = p % 3;
    unsigned int mb = maskbits[n];
    float qv = Q[(size_t)n * DM + tid];

    float s[27];
    float mx = -1e30f;
#pragma unroll
    for (int j = 0; j < 27; ++j) {
        if (mb & (1u << j)) {
            int z = zc + j / 9 - 1;
            int y = yc + (j / 3) % 3 - 1;
            int x = xc + j % 3 - 1;
            int m = b * 27 + z * 9 + y * 3 + x;
            float partial = qv * K[(size_t)m * DM + tid];
            for (int off = 16; off; off >>= 1)
                partial += __shfl_xor(partial, off, 32);
            s[j] = partial * 0.17677669529663687f;   // 1/sqrt(32)
            mx = fmaxf(mx, s[j]);
        } else {
            s[j] = -1e30f;
        }
    }
    float sum = 0.f;
#pragma unroll
    for (int j = 0; j < 27; ++j) {
        if (mb & (1u << j)) { s[j] = expf(s[j] - mx); sum += s[j]; }
        else s[j] = 0.f;
    }
    float inv = (sum > 0.f) ? 1.f / sum : 0.f;
    float o = 0.f;
#pragma unroll
    for (int j = 0; j < 27; ++j) {
        if (mb & (1u << j)) {
            int z = zc + j / 9 - 1;
            int y = yc + (j / 3) % 3 - 1;
            int x = xc + j % 3 - 1;
            int m = b * 27 + z * 9 + y * 3 + x;
            o = fmaf(s[j] * inv, V[(size_t)m * DM + tid], o);
        }
    }
    out[(size_t)n * DM + tid] = __float2bfloat16(o);
}

// ---------------- output: out[b] = t[center(b)] . w_out + b_out ------------
__global__ __launch_bounds__(256) void out_proj_kernel(
    const float* __restrict__ t, const float* __restrict__ w_out,
    const float* __restrict__ b_out, float* __restrict__ out)
{
    int bb = blockIdx.x;
    int c = threadIdx.x;
    float v = t[(size_t)(bb * 27 + 13) * DM + c] * w_out[c];
    for (int off = 32; off; off >>= 1) v += __shfl_xor(v, off);
    __shared__ float ps[4];
    if ((c & 63) == 0) ps[c >> 6] = v;
    __syncthreads();
    if (c == 0) out[bb] = ps[0] + ps[1] + ps[2] + ps[3] + b_out[0];
}

// ---------------------------------------------------------------------------
extern "C" void kernel_launch(void* const* d_in, const int* in_sizes, int n_in,
                              void* d_out, int out_size, void* d_ws, size_t ws_size,
                              hipStream_t stream)
{
    const float* npat  = (const float*)d_in[0];
    const int*   kmask = (const int*)  d_in[1];
    const float* w_in  = (const float*)d_in[2];
    const float* b_in  = (const float*)d_in[3];
    const float* pos   = (const float*)d_in[4];
    const float* ln1_g = (const float*)d_in[5];
    const float* ln1_b = (const float*)d_in[6];
    const float* ln2_g = (const float*)d_in[7];
    const float* ln2_b = (const float*)d_in[8];
    const float* Wq    = (const float*)d_in[9];
    const float* bq    = (const float*)d_in[10];
    const float* Wk    = (const float*)d_in[11];
    const float* bk    = (const float*)d_in[12];
    const float* Wv    = (const float*)d_in[13];
    const float* bv    = (const float*)d_in[14];
    const float* Wo    = (const float*)d_in[15];
    const float* bo    = (const float*)d_in[16];
    const float* W1    = (const float*)d_in[17];
    const float* b1    = (const float*)d_in[18];
    const float* W2    = (const float*)d_in[19];
    const float* b2    = (const float*)d_in[20];
    const float* w_out = (const float*)d_in[21];
    const float* b_out = (const float*)d_in[22];
    float* out = (float*)d_out;

    // workspace carve-up (sizes all multiples of 256B)
    char* ws = (char*)d_ws;
    size_t f32mat = (size_t)NTOK * DM * 4;   // 7,077,888
    size_t bfmat  = (size_t)NTOK * DM * 2;   // 3,538,944
    float* t    = (float*)(ws);
    float* Qf   = (float*)(ws + f32mat);
    float* Kf   = (float*)(ws + 2 * f32mat);
    float* Vf   = (float*)(ws + 3 * f32mat);
    char* p = ws + 4 * f32mat;
    bf16* t_bf   = (bf16*)(p);               p += bfmat;
    bf16* tn_bf  = (bf16*)(p);               p += bfmat;
    bf16* attn_bf= (bf16*)(p);               p += bfmat;
    bf16* H_bf   = (bf16*)(p);               p += (size_t)NTOK * FF * 2;
    bf16* Wt     = (bf16*)(p);               p += (size_t)3 * 786432 * 2;
    unsigned int* maskbits = (unsigned int*)(p);

    convert_weights<<<dim3(32, 32, 18), dim3(32, 8), 0, stream>>>(
        Wq, Wk, Wv, Wo, W1, W2, Wt);
    embed_kernel<<<NTOK, 256, 0, stream>>>(npat, w_in, b_in, pos, t, t_bf);
    make_mask_kernel<<<(NTOK + 255) / 256, 256, 0, stream>>>(kmask, maskbits);

    dim3 gDD(NTOK / 128, DM / 64);    // (54, 4)
    dim3 gFF(NTOK / 128, FF / 64);    // (54, 16)

    for (int l = 0; l < 3; ++l) {
        const bf16* wqt = Wt + (size_t)l * 786432;
        const bf16* wkt = wqt + 65536;
        const bf16* wvt = wkt + 65536;
        const bf16* wot = wvt + 65536;
        const bf16* w1t = wot + 65536;
        const bf16* w2t = w1t + 262144;

        layernorm_kernel<<<NTOK, 256, 0, stream>>>(t, ln1_g + l * DM, ln1_b + l * DM, tn_bf);
        gemm_bf16<<<gDD, 256, 0, stream>>>(tn_bf, wqt, bq + l * DM, nullptr, Qf, nullptr, DM, DM, 0);
        gemm_bf16<<<gDD, 256, 0, stream>>>(t_bf, wkt, bk + l * DM, nullptr, Kf, nullptr, DM, DM, 0);
        gemm_bf16<<<gDD, 256, 0, stream>>>(t_bf, wvt, bv + l * DM, nullptr, Vf, nullptr, DM, DM, 0);
        attention_kernel<<<NTOK, 256, 0, stream>>>(Qf, Kf, Vf, maskbits, attn_bf);
        gemm_bf16<<<gDD, 256, 0, stream>>>(attn_bf, wot, bo + l * DM, t, t, t_bf, DM, DM, 0);
        layernorm_kernel<<<NTOK, 256, 0, stream>>>(t, ln2_g + l * DM, ln2_b + l * DM, tn_bf);
        gemm_bf16<<<gFF, 256, 0, stream>>>(tn_bf, w1t, b1 + l * FF, nullptr, nullptr, H_bf, DM, FF, 1);
        gemm_bf16<<<gDD, 256, 0, stream>>>(H_bf, w2t, b2 + l * DM, t, t, t_bf, FF, DM, 0);
    }

    out_proj_kernel<<<256, 256, 0, stream>>>(t, w_out, b_out, out);
}